// Round 1
// baseline (844.675 us; speedup 1.0000x reference)
//
#include <hip/hip_runtime.h>

#define TN 2048

// ---------------- prep: transpose weights into d_ws ----------------
// w1 [256][128] -> w1T [128][256] (c-major);  w2 [10][256] -> w2T [256][16] (h-major, padded)
__global__ __launch_bounds__(256)
void prep_kernel(const float* __restrict__ w1, const float* __restrict__ w2,
                 float* __restrict__ w1T, float* __restrict__ w2T) {
    int bid = blockIdx.x;
    if (bid < 32) {
        __shared__ float tile[32][33];
        int h0 = (bid >> 2) << 5;      // 8 tiles along h (256)
        int c0 = (bid & 3) << 5;       // 4 tiles along c (128)
        int tx = threadIdx.x & 31, ty = threadIdx.x >> 5;   // 32 x 8
        #pragma unroll
        for (int i = ty; i < 32; i += 8)
            tile[i][tx] = w1[(h0 + i) * 128 + (c0 + tx)];
        __syncthreads();
        #pragma unroll
        for (int i = ty; i < 32; i += 8)
            w1T[(c0 + i) * 256 + (h0 + tx)] = tile[tx][i];  // w1T[c][h] = w1[h][c]
    } else {
        for (int idx = threadIdx.x; idx < 256 * 16; idx += 256) {
            int h = idx >> 4, n = idx & 15;
            w2T[idx] = (n < 10) ? w2[n * 256 + h] : 0.0f;
        }
    }
}

// ---------------- main: one wave per batch, full 2048-step scan ----------------
__global__ __launch_bounds__(256, 1)
void snn_main(const float* __restrict__ x,
              const float* __restrict__ convw,
              const float* __restrict__ w1T,
              const float* __restrict__ w2T,
              float* __restrict__ out) {
    extern __shared__ float lds[];
    float* w1L = lds;                // [128][256]  131072 B
    float* w2L = lds + 32768;        // [256][16]    16384 B
    float* xL  = lds + 36864;        // [2064]       8256 B  (idx i <-> x[i-3], zero padded)

    const int b = blockIdx.x;
    const int tid = threadIdx.x;

    // stage weights (coalesced float4 reads, conflict-free LDS writes)
    {
        const float4* s4 = (const float4*)w1T;
        float4* d4 = (float4*)w1L;
        for (int i = tid; i < 8192; i += 256) d4[i] = s4[i];
        const float4* s2 = (const float4*)w2T;
        float4* d2 = (float4*)w2L;
        for (int i = tid; i < 1024; i += 256) d2[i] = s2[i];
    }
    for (int i = tid; i < 2064; i += 256) {
        int l = i - 3;
        xL[i] = (l >= 0 && l < TN) ? x[b * TN + l] : 0.0f;
    }
    __syncthreads();
    if (tid >= 64) return;           // scan runs on wave 0 only (no barriers needed)

    const int lane = tid;

    // conv weights for this lane's two channels: c = lane, lane + 64
    float cwa[7], cwb[7];
    #pragma unroll
    for (int k = 0; k < 7; ++k) {
        cwa[k] = convw[lane * 7 + k];
        cwb[k] = convw[(lane + 64) * 7 + k];
    }

    // membrane state
    float v1a = 0.f, v1b = 0.f;                       // c = lane, lane+64
    float v20 = 0.f, v21 = 0.f, v22 = 0.f, v23 = 0.f; // h = lane + 64*j
    float v3 = 0.f, acc = 0.f;                        // n = lane (<10)

    // sliding x window: xw[0..11] = xL[tb .. tb+11]
    float xw[12];
    {
        float4 f0 = *(const float4*)(xL + 0);
        float4 f1 = *(const float4*)(xL + 4);
        float4 f2 = *(const float4*)(xL + 8);
        *(float4*)&xw[0] = f0; *(float4*)&xw[4] = f1; *(float4*)&xw[8] = f2;
    }

    const float* w2base = w2L + (lane & 15);

    for (int tb = 0; tb < TN; tb += 4) {
        // prefetch next quad (aligned b128, broadcast; max idx 2059 < 2064)
        float4 fn = *(const float4*)(xL + tb + 12);

        #pragma unroll
        for (int p = 0; p < 4; ++p) {
            // ---- layer 1: conv (rounded separately, like the reference) + IF ----
            float xca = 0.f, xcb = 0.f;
            #pragma unroll
            for (int k = 0; k < 7; ++k) {
                float xv = xw[p + k];
                xca = fmaf(xv, cwa[k], xca);
                xcb = fmaf(xv, cwb[k], xcb);
            }
            float na = v1a + xca, nb = v1b + xcb;
            bool sa = na >= 1.0f, sb = nb >= 1.0f;
            unsigned long long ma = __ballot(sa);   // bit l <-> c = l
            unsigned long long mb = __ballot(sb);   // bit l <-> c = 64 + l
            v1a = sa ? 0.f : na;
            v1b = sb ? 0.f : nb;

            if (ma | mb) {
                // ---- layer 2: sparse gather of w1 columns, ascending c ----
                float i0 = 0.f, i1 = 0.f, i2 = 0.f, i3 = 0.f;
                unsigned long long m = ma;
                while (m) {
                    int c = __builtin_ctzll(m); m &= m - 1;
                    const float* wr = w1L + (c << 8) + lane;
                    i0 += wr[0]; i1 += wr[64]; i2 += wr[128]; i3 += wr[192];
                }
                m = mb;
                while (m) {
                    int c = __builtin_ctzll(m); m &= m - 1;
                    const float* wr = w1L + ((c + 64) << 8) + lane;
                    i0 += wr[0]; i1 += wr[64]; i2 += wr[128]; i3 += wr[192];
                }
                float n0 = v20 + i0, n1 = v21 + i1, n2 = v22 + i2, n3 = v23 + i3;
                bool s0 = n0 >= 1.0f, s1 = n1 >= 1.0f, s2 = n2 >= 1.0f, s3 = n3 >= 1.0f;
                unsigned long long h0 = __ballot(s0);  // h = l
                unsigned long long h1 = __ballot(s1);  // h = 64 + l
                unsigned long long h2 = __ballot(s2);  // h = 128 + l
                unsigned long long h3 = __ballot(s3);  // h = 192 + l
                v20 = s0 ? 0.f : n0; v21 = s1 ? 0.f : n1;
                v22 = s2 ? 0.f : n2; v23 = s3 ? 0.f : n3;

                if (h0 | h1 | h2 | h3) {
                    // ---- layer 3: sparse gather of w2 rows, ascending h ----
                    float inc3 = 0.f;
                    unsigned long long mm = h0;
                    while (mm) { int h = __builtin_ctzll(mm); mm &= mm - 1; inc3 += w2base[h << 4]; }
                    mm = h1;
                    while (mm) { int h = 64 + __builtin_ctzll(mm); mm &= mm - 1; inc3 += w2base[h << 4]; }
                    mm = h2;
                    while (mm) { int h = 128 + __builtin_ctzll(mm); mm &= mm - 1; inc3 += w2base[h << 4]; }
                    mm = h3;
                    while (mm) { int h = 192 + __builtin_ctzll(mm); mm &= mm - 1; inc3 += w2base[h << 4]; }
                    float nn = v3 + inc3;
                    bool ss = nn >= 1.0f;
                    v3 = ss ? 0.f : nn;
                    acc += ss ? 1.0f : 0.0f;
                }
            }
        }
        // shift window by 4
        #pragma unroll
        for (int i = 0; i < 8; ++i) xw[i] = xw[i + 4];
        *(float4*)&xw[8] = fn;
    }

    if (lane < 10) out[b * 10 + lane] = acc * (1.0f / 2048.0f);
}

extern "C" void kernel_launch(void* const* d_in, const int* in_sizes, int n_in,
                              void* d_out, int out_size, void* d_ws, size_t ws_size,
                              hipStream_t stream) {
    const float* x     = (const float*)d_in[0];
    const float* convw = (const float*)d_in[1];
    const float* w1    = (const float*)d_in[2];
    const float* w2    = (const float*)d_in[3];
    float* w1T = (float*)d_ws;                 // 131072 B
    float* w2T = (float*)d_ws + 32768;         // 16384 B

    prep_kernel<<<33, 256, 0, stream>>>(w1, w2, w1T, w2T);

    const size_t ldsz = (32768 + 4096 + 2064) * sizeof(float);   // 155712 B
    (void)hipFuncSetAttribute(reinterpret_cast<const void*>(snn_main),
                              hipFuncAttributeMaxDynamicSharedMemorySize, (int)ldsz);
    snn_main<<<128, 256, ldsz, stream>>>(x, convw, w1T, w2T, (float*)d_out);
}